// Round 1
// baseline (85.560 us; speedup 1.0000x reference)
//
#include <hip/hip_runtime.h>

// Problem constants (fixed by the reference):
//   input:  (1, 256, 512, 512) f32
//   state:  (1, 256, 256, 256) f32
//   change: (32768,) i32 flat spatial indices y*W + x
#define C_  256
#define H_  512
#define W_  512
#define OH_ 256
#define OW_ 256
// mask: 1 bit per output spatial pixel -> OH*OW/32 = 2048 u32 = 8 KB (in d_ws)

__global__ void cbpool_set_mask(const int* __restrict__ change, int K,
                                unsigned int* __restrict__ mask) {
    int k = blockIdx.x * blockDim.x + threadIdx.x;
    if (k >= K) return;
    int idx = change[k];
    // y = idx / W, x = idx % W  (W = 512 = 2^9)
    int y = idx >> 9;
    int x = idx & (W_ - 1);
    int oy = y >> 1;
    int ox = x >> 1;
    int bit = oy * OW_ + ox;
    atomicOr(&mask[bit >> 5], 1u << (bit & 31));
}

// One thread per PAIR of horizontally-adjacent output pixels.
// Reads: 2x float4 from input (coalesced 16B/lane), float2 state, 1 mask word.
// Writes: float2 output. Fully dense + coalesced; mask selects pooled vs state.
__global__ void cbpool_fused(const float* __restrict__ in,
                             const float* __restrict__ state,
                             const unsigned int* __restrict__ mask,
                             float* __restrict__ out) {
    int tid = blockIdx.x * blockDim.x + threadIdx.x;   // 0 .. C*OH*(OW/2)-1
    int p  = tid & (OW_ / 2 - 1);      // pair index along output row, 0..127
    int oy = (tid >> 7) & (OH_ - 1);   // output row
    int c  = tid >> 15;                // channel

    const float* inrow = in + (size_t)c * (H_ * W_) + (size_t)(2 * oy) * W_ + 4 * p;
    float4 r0 = *reinterpret_cast<const float4*>(inrow);
    float4 r1 = *reinterpret_cast<const float4*>(inrow + W_);

    float p0 = fmaxf(fmaxf(r0.x, r0.y), fmaxf(r1.x, r1.y));
    float p1 = fmaxf(fmaxf(r0.z, r0.w), fmaxf(r1.z, r1.w));

    size_t obase = (size_t)c * (OH_ * OW_) + (size_t)oy * OW_ + 2 * p;
    float2 s = *reinterpret_cast<const float2*>(state + obase);

    int bit = oy * OW_ + 2 * p;              // even, so bit and bit+1 share a word
    unsigned int m = mask[bit >> 5];
    int sh = bit & 31;

    float2 o;
    o.x = ((m >> sh) & 1u) ? p0 : s.x;
    o.y = ((m >> (sh + 1)) & 1u) ? p1 : s.y;
    *reinterpret_cast<float2*>(out + obase) = o;
}

extern "C" void kernel_launch(void* const* d_in, const int* in_sizes, int n_in,
                              void* d_out, int out_size, void* d_ws, size_t ws_size,
                              hipStream_t stream) {
    const float* in     = (const float*)d_in[0];
    const float* state  = (const float*)d_in[1];
    const int*   change = (const int*)d_in[2];
    float*       out    = (float*)d_out;
    unsigned int* mask  = (unsigned int*)d_ws;   // 8 KB used

    const int K = in_sizes[2];

    // 1) clear mask (graph-capture legal: async memset node on stream)
    hipMemsetAsync(mask, 0, (OH_ * OW_ / 32) * sizeof(unsigned int), stream);

    // 2) set changed bits
    cbpool_set_mask<<<(K + 255) / 256, 256, 0, stream>>>(change, K, mask);

    // 3) fused dense pool + select + write
    const int total_pairs = C_ * OH_ * (OW_ / 2);      // 8,388,608
    cbpool_fused<<<total_pairs / 256, 256, 0, stream>>>(in, state, mask, out);
}

// Round 2
// 76.514 us; speedup vs baseline: 1.1182x; 1.1182x over previous
//
#include <hip/hip_runtime.h>

// Problem constants (fixed by the reference):
//   input:  (1, 256, 512, 512) f32
//   state:  (1, 256, 256, 256) f32
//   change: (32768,) i32 flat spatial indices y*W + x
#define C_  256
#define H_  512
#define W_  512
#define OH_ 256
#define OW_ 256
// mask: 1 bit per output spatial pixel -> OH*OW/32 = 2048 u32 = 8 KB (in d_ws)

typedef float f4 __attribute__((ext_vector_type(4)));

__device__ __forceinline__ f4 ntload4(const float* p) {
    return __builtin_nontemporal_load(reinterpret_cast<const f4*>(p));
}
__device__ __forceinline__ void ntstore4(float* p, f4 v) {
    __builtin_nontemporal_store(v, reinterpret_cast<f4*>(p));
}

__global__ void cbpool_set_mask(const int* __restrict__ change, int K,
                                unsigned int* __restrict__ mask) {
    int k = blockIdx.x * blockDim.x + threadIdx.x;
    if (k >= K) return;
    int idx = change[k];
    int y = idx >> 9;            // W = 512 = 2^9
    int x = idx & (W_ - 1);
    int bit = (y >> 1) * OW_ + (x >> 1);
    atomicOr(&mask[bit >> 5], 1u << (bit & 31));
}

// One thread per QUAD of horizontally-adjacent output pixels (float4 out).
// Reads: 4x float4 input (two rows x 32B), float4 state, 1 mask word.
// All bulk traffic non-temporal (streamed once, working set >> LLC).
__global__ void __launch_bounds__(256)
cbpool_fused(const float* __restrict__ in,
             const float* __restrict__ state,
             const unsigned int* __restrict__ mask,
             float* __restrict__ out) {
    int tid = blockIdx.x * blockDim.x + threadIdx.x;   // 0 .. C*OH*(OW/4)-1
    int q  = tid & 63;                 // quad index along output row, 0..63
    int oy = (tid >> 6) & (OH_ - 1);   // output row
    int c  = tid >> 14;                // channel

    // input row pair base: c*H*W + (2*oy)*W + 8*q
    const float* inrow = in + ((size_t)c << 18) + ((size_t)oy << 10) + (q << 3);
    f4 a0 = ntload4(inrow);
    f4 a1 = ntload4(inrow + 4);
    f4 b0 = ntload4(inrow + W_);
    f4 b1 = ntload4(inrow + W_ + 4);

    f4 pooled;
    pooled.x = fmaxf(fmaxf(a0.x, a0.y), fmaxf(b0.x, b0.y));
    pooled.y = fmaxf(fmaxf(a0.z, a0.w), fmaxf(b0.z, b0.w));
    pooled.z = fmaxf(fmaxf(a1.x, a1.y), fmaxf(b1.x, b1.y));
    pooled.w = fmaxf(fmaxf(a1.z, a1.w), fmaxf(b1.z, b1.w));

    size_t obase = ((size_t)c << 16) + (oy << 8) + (q << 2);
    f4 s = ntload4(state + obase);

    unsigned int m = mask[(oy << 3) + (q >> 3)];   // 4 bits for this quad share a word
    int sh = (q << 2) & 31;

    f4 o;
    o.x = ((m >> (sh + 0)) & 1u) ? pooled.x : s.x;
    o.y = ((m >> (sh + 1)) & 1u) ? pooled.y : s.y;
    o.z = ((m >> (sh + 2)) & 1u) ? pooled.z : s.z;
    o.w = ((m >> (sh + 3)) & 1u) ? pooled.w : s.w;
    ntstore4(out + obase, o);
}

extern "C" void kernel_launch(void* const* d_in, const int* in_sizes, int n_in,
                              void* d_out, int out_size, void* d_ws, size_t ws_size,
                              hipStream_t stream) {
    const float* in     = (const float*)d_in[0];
    const float* state  = (const float*)d_in[1];
    const int*   change = (const int*)d_in[2];
    float*       out    = (float*)d_out;
    unsigned int* mask  = (unsigned int*)d_ws;   // 8 KB used

    const int K = in_sizes[2];

    hipMemsetAsync(mask, 0, (OH_ * OW_ / 32) * sizeof(unsigned int), stream);
    cbpool_set_mask<<<(K + 255) / 256, 256, 0, stream>>>(change, K, mask);

    const int total_quads = C_ * OH_ * (OW_ / 4);      // 4,194,304
    cbpool_fused<<<total_quads / 256, 256, 0, stream>>>(in, state, mask, out);
}